// Round 6
// baseline (958.570 us; speedup 1.0000x reference)
//
#include <hip/hip_runtime.h>

// ---------------- problem constants ----------------
#define NROWS   131072
#define KDIM    1024
#define NLVL    4
#define SLOT_CAP 132096            // 131072 + 4*256 padding
#define NSB     516                // SLOT_CAP / 256 slot-blocks
#define NNB     8                  // 1024 cols / 128

// ---------------- ws layout (bytes) ----------------
#define OFF_IDX  1024ull
#define OFF_PART (OFF_IDX + (size_t)SLOT_CAP * 4)
#define OFF_WT1  (OFF_PART + (size_t)SLOT_CAP * 64)
#define OFF_WT2  (OFF_WT1 + 8388608ull)
#define OFF_XBF  (OFF_WT2 + 8388608ull)
#define OFF_H1   (OFF_XBF + 268435456ull)

typedef __bf16 bf16x8 __attribute__((ext_vector_type(8)));
typedef float f32x4 __attribute__((ext_vector_type(4)));
typedef unsigned short u16x4 __attribute__((ext_vector_type(4)));

__device__ __forceinline__ unsigned short f2bf(float f) {
  unsigned int u = __float_as_uint(f);
  u += 0x7fffu + ((u >> 16) & 1u);       // RNE
  return (unsigned short)(u >> 16);
}

__device__ __forceinline__ void gld_lds16(const void* g, void* l) {
  __builtin_amdgcn_global_load_lds(
      (const __attribute__((address_space(1))) void*)g,
      (__attribute__((address_space(3))) void*)l, 16, 0, 0);
}

// meta layout (ints): [0..3]=counts [4..7]=cursors [8..11]=seg [12..15]=padded counts

__global__ void k_hist(const int* __restrict__ levels, int n, int* __restrict__ meta) {
  __shared__ int h[NLVL];
  if (threadIdx.x < NLVL) h[threadIdx.x] = 0;
  __syncthreads();
  for (int t = blockIdx.x * blockDim.x + threadIdx.x; t < n; t += gridDim.x * blockDim.x)
    atomicAdd(&h[levels[t]], 1);
  __syncthreads();
  if (threadIdx.x < NLVL) atomicAdd(&meta[threadIdx.x], h[threadIdx.x]);
}

__global__ void k_seg(int* meta) {
  if (threadIdx.x == 0 && blockIdx.x == 0) {
    int s = 0;
    for (int l = 0; l < NLVL; ++l) {
      int pc = (meta[l] + 255) & ~255;
      meta[8 + l] = s;
      meta[12 + l] = pc;
      s += pc;
    }
  }
}

__global__ void k_scatter(const int* __restrict__ levels, int n,
                          int* __restrict__ meta, int* __restrict__ idx) {
  __shared__ int h[NLVL], base[NLVL], cur[NLVL];
  int t = blockIdx.x * blockDim.x + threadIdx.x;
  if (threadIdx.x < NLVL) { h[threadIdx.x] = 0; cur[threadIdx.x] = 0; }
  __syncthreads();
  int lvl = 0;
  if (t < n) { lvl = levels[t]; atomicAdd(&h[lvl], 1); }
  __syncthreads();
  if (threadIdx.x < NLVL)
    base[threadIdx.x] = atomicAdd(&meta[4 + threadIdx.x], h[threadIdx.x]);
  __syncthreads();
  if (t < n) {
    int p = atomicAdd(&cur[lvl], 1);
    idx[meta[8 + lvl] + base[lvl] + p] = t;
  }
}

__global__ void k_cvt_x(const f32x4* __restrict__ x, u16x4* __restrict__ xb, int n4) {
  for (int t = blockIdx.x * blockDim.x + threadIdx.x; t < n4; t += gridDim.x * blockDim.x) {
    f32x4 v = x[t];
    u16x4 o;
    o[0] = f2bf(v[0]); o[1] = f2bf(v[1]); o[2] = f2bf(v[2]); o[3] = f2bf(v[3]);
    xb[t] = o;
  }
}

// transpose-convert W[lvl][k][n] (fp32) -> Wt[lvl][n][k] (bf16)
__global__ void k_twt(const float* __restrict__ W, unsigned short* __restrict__ Wt) {
  __shared__ float tile[32][33];
  int lvl = blockIdx.z;
  int k0 = blockIdx.x * 32, n0 = blockIdx.y * 32;
  int tx = threadIdx.x, ty = threadIdx.y;
  const float* Wp = W + (size_t)lvl * 1048576;
  unsigned short* Wtp = Wt + (size_t)lvl * 1048576;
#pragma unroll
  for (int i = 0; i < 4; ++i)
    tile[ty + i * 8][tx] = Wp[(size_t)(k0 + ty + i * 8) * 1024 + n0 + tx];
  __syncthreads();
#pragma unroll
  for (int i = 0; i < 4; ++i) {
    int nn = ty + i * 8;
    Wtp[(size_t)(n0 + nn) * 1024 + k0 + tx] = f2bf(tile[tx][nn]);
  }
}

// ---------------------------------------------------------------------------
// 256(m) x 128(n) grouped GEMM, BK=64, 8 waves (4m x 2n), per-wave 64x64,
// mfma 16x16x32 bf16, acc[4][4] f32x4. 3-deep LDS pipeline (144KB).
// Per phase: 8 ds_read_b128 + 3 gld_lds16 | barrier | lgkmcnt(0) | 16 MFMA |
// counted vmcnt | barrier. 3 loads/wave/phase; steady-state vmcnt(9) = 3
// phases in flight (stage->consume gap = 4 phases, ledger exactly tight).
// TAIL FIX (round-5 tripwire): staging stops after t=13, so the all-but-9
// window stops sliding; tiles 14/15 must DRAIN: vmcnt 6 -> 3 -> 0 at the
// ends of t14A/t14B/t15A so each tail read's staging loads (#88-96) are
// covered. Uniform vmcnt(9) there left loads 88-96 unguaranteed -> the
// intermittent replay divergence.
// Barriers are asm s_barrier with "memory" clobber (round-4 lesson: the raw
// builtin is not a compiler fence; hoisted ds_reads void the cross-wave
// {vmcnt -> barrier -> read} guarantee).
// XCD-chunked grid (nb innermost): per XCD round = 4 sb x 8 nb ->
// L2 working set = 2MB X (streaming, 8-way reuse) + 2MB W (hot) = fits 4MB.
// ---------------------------------------------------------------------------
#define BARRM   asm volatile("s_barrier" ::: "memory")
#define WAIT_L  asm volatile("s_waitcnt lgkmcnt(0)" ::: "memory")
#define WAIT_V9 asm volatile("s_waitcnt vmcnt(9)" ::: "memory")
#define WAIT_V6 asm volatile("s_waitcnt vmcnt(6)" ::: "memory")
#define WAIT_V3 asm volatile("s_waitcnt vmcnt(3)" ::: "memory")
#define WAIT_V0 asm volatile("s_waitcnt vmcnt(0)" ::: "memory")
#define PRIO(x) __builtin_amdgcn_s_setprio(x)

#define RDW(p,kk) { const char* p_ = lds + (p)*49152 + 32768 + (kk)*8192 + offW; \
  wf[0] = *(const bf16x8*)(p_);        wf[1] = *(const bf16x8*)(p_ + 1024);     \
  wf[2] = *(const bf16x8*)(p_ + 2048); wf[3] = *(const bf16x8*)(p_ + 3072); }
#define RDX(p,kk) { const char* p_ = lds + (p)*49152 + (kk)*16384 + offX;       \
  xf[0] = *(const bf16x8*)(p_);        xf[1] = *(const bf16x8*)(p_ + 1024);     \
  xf[2] = *(const bf16x8*)(p_ + 2048); xf[3] = *(const bf16x8*)(p_ + 3072); }
#define MMA4 { _Pragma("unroll") for (int nf_ = 0; nf_ < 4; ++nf_) { \
  _Pragma("unroll") for (int mf_ = 0; mf_ < 4; ++mf_) \
    acc[nf_][mf_] = __builtin_amdgcn_mfma_f32_16x16x32_bf16(wf[nf_], xf[mf_], acc[nf_][mf_], 0, 0, 0); } }
#define STGW(p,t,kk) gld_lds16(ws0 + (t)*128 + (kk)*64, \
  (char*)lds + (p)*49152 + 32768 + (kk)*8192 + (w << 10))
#define STGX(p,t,kk) { char* d_ = (char*)lds + (p)*49152 + (kk)*16384 + (w << 10); \
  gld_lds16(xs0 + (t)*128 + (kk)*64, d_); \
  gld_lds16(xs1 + (t)*128 + (kk)*64, d_ + 8192); }

template <int PASS>
__global__ __launch_bounds__(512, 2) void k_gemm(
    const unsigned short* __restrict__ Asrc,
    const unsigned short* __restrict__ Wt,
    const float* __restrict__ bias,
    const float* __restrict__ w3,
    const int* __restrict__ meta,
    const int* __restrict__ idx,
    unsigned short* __restrict__ hout,
    float* __restrict__ partial) {
  __shared__ __align__(16) char lds[147456];

  // XCD-chunked bijective swizzle over NSB*8 = 4128 blocks (4128 % 8 == 0).
  const int bid = blockIdx.x;
  const int swz = (bid & 7) * NSB + (bid >> 3);
  const int nb = swz & 7;
  const int sb = swz >> 3;
  const int slotbase = sb * 256;
  if (slotbase >= meta[11] + meta[15]) return;
  int lvl;
  if      (slotbase < meta[9])  lvl = 0;
  else if (slotbase < meta[10]) lvl = 1;
  else if (slotbase < meta[11]) lvl = 2;
  else                          lvl = 3;

  const int tid = threadIdx.x;
  const int ln  = tid & 63;
  const int w   = tid >> 6;          // wave 0..7
  const int wm  = w & 3;             // m-quadrant (4 x 64 rows)
  const int wn  = w >> 2;            // n-half (2 x 64 cols)
  const int l15 = ln & 15;

  // ---- staging lane constants: wave w stages rows w*16..w*16+15 ----
  const int srow = w * 16 + (ln >> 2);           // 0..127
  const int cch  = (ln & 3) ^ ((srow >> 1) & 3); // pre-swizzled source chunk
  int ar0, ar1;
  if (PASS == 1) { ar0 = idx[slotbase + srow]; ar1 = idx[slotbase + srow + 128]; }
  else           { ar0 = slotbase + srow;      ar1 = slotbase + srow + 128; }
  const char* xs0 = (const char*)Asrc + (size_t)ar0 * 2048 + cch * 16;
  const char* xs1 = (const char*)Asrc + (size_t)ar1 * 2048 + cch * 16;
  const char* ws0 = (const char*)Wt + ((size_t)lvl << 21)
                    + (size_t)(nb * 128 + srow) * 2048 + cch * 16;

  // ---- fragment read offsets (same XOR; +16 rows = +1024B) ----
  const int xorc = ((ln >> 4) ^ ((l15 >> 1) & 3)) * 16;
  const int offX = wm * 4096 + l15 * 64 + xorc;
  const int offW = wn * 4096 + l15 * 64 + xorc;

  const f32x4 vzero = {0.f, 0.f, 0.f, 0.f};
  f32x4 acc[4][4];
#pragma unroll
  for (int a = 0; a < 4; ++a)
#pragma unroll
    for (int b = 0; b < 4; ++b) acc[a][b] = vzero;
  bf16x8 wf[4], xf[4];

  // ---- prologue: stage tiles 0 and 1 (6 loads each) ----
  STGW(0, 0, 0); STGX(0, 0, 0); STGW(0, 0, 1); STGX(0, 0, 1);
  STGW(1, 1, 0); STGX(1, 1, 0); STGW(1, 1, 1); STGX(1, 1, 1);
  WAIT_V6;                                            // tile0's 6 loads landed
  BARRM;

  // ---- steady state: tiles 0..13, staging t+2 ----
#pragma unroll
  for (int t = 0; t < 14; ++t) {
    const int p  = t % 3;
    const int ps = (t + 2) % 3;
    // phase A (kk=0)
    RDW(p, 0); RDX(p, 0);
    STGW(ps, t + 2, 0); STGX(ps, t + 2, 0);
    BARRM; WAIT_L; PRIO(1); MMA4; PRIO(0); WAIT_V9; BARRM;
    // phase B (kk=1)
    RDW(p, 1); RDX(p, 1);
    STGW(ps, t + 2, 1); STGX(ps, t + 2, 1);
    BARRM; WAIT_L; PRIO(1); MMA4; PRIO(0); WAIT_V9; BARRM;
  }

  // ---- tail: tiles 14 (parity 2) and 15 (parity 0), draining vmcnt ----
  RDW(2, 0); RDX(2, 0);
  BARRM; WAIT_L; PRIO(1); MMA4; PRIO(0); WAIT_V6; BARRM;   // -> loads #90 done
  RDW(2, 1); RDX(2, 1);
  BARRM; WAIT_L; PRIO(1); MMA4; PRIO(0); WAIT_V3; BARRM;   // -> #93 done
  RDW(0, 0); RDX(0, 0);
  BARRM; WAIT_L; PRIO(1); MMA4; PRIO(0); WAIT_V0; BARRM;   // -> #96 done
  RDW(0, 1); RDX(0, 1);
  WAIT_L; PRIO(1); MMA4; PRIO(0);

  // ---- epilogue ----
  const float* bv = bias + lvl * 1024;
  const int n_lo = (ln >> 4) * 4;

  if (PASS == 1) {
#pragma unroll
    for (int nf = 0; nf < 4; ++nf) {
#pragma unroll
      for (int mf = 0; mf < 4; ++mf) {
        int slot = slotbase + wm * 64 + mf * 16 + l15;
        int col = nb * 128 + wn * 64 + nf * 16 + n_lo;
        f32x4 bb = *(const f32x4*)&bv[col];
        f32x4 v = acc[nf][mf];
        u16x4 o;
#pragma unroll
        for (int r = 0; r < 4; ++r) o[r] = f2bf(fmaxf(v[r] + bb[r], 0.f));
        *(u16x4*)&hout[(size_t)slot * 1024 + col] = o;
      }
    }
  } else {
    const float* w3v = w3 + lvl * 1024;
    float ps4[4] = {0.f, 0.f, 0.f, 0.f};
#pragma unroll
    for (int mf = 0; mf < 4; ++mf) {
#pragma unroll
      for (int nf = 0; nf < 4; ++nf) {
        int col = nb * 128 + wn * 64 + nf * 16 + n_lo;
        f32x4 bb = *(const f32x4*)&bv[col];
        f32x4 ww = *(const f32x4*)&w3v[col];
        f32x4 v = acc[nf][mf];
#pragma unroll
        for (int r = 0; r < 4; ++r) ps4[mf] += fmaxf(v[r] + bb[r], 0.f) * ww[r];
      }
    }
#pragma unroll
    for (int mf = 0; mf < 4; ++mf) {
      float p = ps4[mf];
      p += __shfl_xor(p, 16);
      p += __shfl_xor(p, 32);
      if (ln < 16) {
        int slot = slotbase + wm * 64 + mf * 16 + ln;
        partial[(size_t)slot * 16 + nb * 2 + wn] = p;
      }
    }
  }
}

__global__ void k_final(const int* __restrict__ meta, const int* __restrict__ idx,
                        const float* __restrict__ partial, const float* __restrict__ b3,
                        float* __restrict__ out) {
  int t = blockIdx.x * blockDim.x + threadIdx.x;
  int total = meta[11] + meta[15];
  if (t >= total) return;
  int lvl;
  if (t < meta[9]) lvl = 0;
  else if (t < meta[10]) lvl = 1;
  else if (t < meta[11]) lvl = 2;
  else lvl = 3;
  int local = t - meta[8 + lvl];
  if (local >= meta[lvl]) return;  // padding slot
  int row = idx[t];
  const float* pp = partial + (size_t)t * 16;
  float s = 0.f;
#pragma unroll
  for (int j = 0; j < 16; ++j) s += pp[j];
  out[row] = s + b3[lvl];
}

extern "C" void kernel_launch(void* const* d_in, const int* in_sizes, int n_in,
                              void* d_out, int out_size, void* d_ws, size_t ws_size,
                              hipStream_t stream) {
  const float* x      = (const float*)d_in[0];
  const int*   levels = (const int*)d_in[1];
  const float* W1     = (const float*)d_in[2];
  const float* b1     = (const float*)d_in[3];
  const float* W2     = (const float*)d_in[4];
  const float* b2     = (const float*)d_in[5];
  const float* W3     = (const float*)d_in[6];
  const float* b3     = (const float*)d_in[7];
  float* out = (float*)d_out;

  char* ws = (char*)d_ws;
  int* meta = (int*)ws;
  int* idx = (int*)(ws + OFF_IDX);
  float* partial = (float*)(ws + OFF_PART);
  unsigned short* Wt1 = (unsigned short*)(ws + OFF_WT1);
  unsigned short* Wt2 = (unsigned short*)(ws + OFF_WT2);
  unsigned short* xb  = (unsigned short*)(ws + OFF_XBF);
  unsigned short* h1  = (unsigned short*)(ws + OFF_H1);

  // zero meta + idx (padding slots -> row 0, safe finite data)
  hipMemsetAsync(d_ws, 0, OFF_IDX + (size_t)SLOT_CAP * 4, stream);
  k_hist<<<256, 256, 0, stream>>>(levels, NROWS, meta);
  k_seg<<<1, 64, 0, stream>>>(meta);
  k_scatter<<<512, 256, 0, stream>>>(levels, NROWS, meta, idx);
  k_cvt_x<<<2048, 256, 0, stream>>>((const f32x4*)x, (u16x4*)xb, NROWS * (KDIM / 4));
  k_twt<<<dim3(32, 32, 4), dim3(32, 8), 0, stream>>>(W1, Wt1);
  k_twt<<<dim3(32, 32, 4), dim3(32, 8), 0, stream>>>(W2, Wt2);

  k_gemm<1><<<NSB * NNB, 512, 0, stream>>>(xb, Wt1, b1, nullptr, meta, idx, h1, nullptr);
  k_gemm<2><<<NSB * NNB, 512, 0, stream>>>(h1, Wt2, b2, W3, meta, idx, nullptr, partial);

  k_final<<<516, 256, 0, stream>>>(meta, idx, partial, b3, out);
}

// Round 7
// 829.785 us; speedup vs baseline: 1.1552x; 1.1552x over previous
//
#include <hip/hip_runtime.h>

// ---------------- problem constants ----------------
#define NROWS   131072
#define KDIM    1024
#define NLVL    4
#define SLOT_CAP 132096            // 131072 + 4*256 padding
#define NSB     516                // SLOT_CAP / 256 slot-blocks
#define NNB     4                  // 1024 cols / 256

// ---------------- ws layout (bytes) ----------------
#define OFF_IDX  1024ull
#define OFF_PART (OFF_IDX + (size_t)SLOT_CAP * 4)
#define OFF_WT1  (OFF_PART + (size_t)SLOT_CAP * 64)
#define OFF_WT2  (OFF_WT1 + 8388608ull)
#define OFF_XBF  (OFF_WT2 + 8388608ull)
#define OFF_H1   (OFF_XBF + 268435456ull)

typedef __bf16 bf16x8 __attribute__((ext_vector_type(8)));
typedef float f32x4 __attribute__((ext_vector_type(4)));
typedef unsigned short u16x4 __attribute__((ext_vector_type(4)));

__device__ __forceinline__ unsigned short f2bf(float f) {
  unsigned int u = __float_as_uint(f);
  u += 0x7fffu + ((u >> 16) & 1u);       // RNE
  return (unsigned short)(u >> 16);
}

__device__ __forceinline__ void gld_lds16(const void* g, void* l) {
  __builtin_amdgcn_global_load_lds(
      (const __attribute__((address_space(1))) void*)g,
      (__attribute__((address_space(3))) void*)l, 16, 0, 0);
}

// meta layout (ints): [0..3]=counts [4..7]=cursors [8..11]=seg [12..15]=padded counts

__global__ void k_hist(const int* __restrict__ levels, int n, int* __restrict__ meta) {
  __shared__ int h[NLVL];
  if (threadIdx.x < NLVL) h[threadIdx.x] = 0;
  __syncthreads();
  for (int t = blockIdx.x * blockDim.x + threadIdx.x; t < n; t += gridDim.x * blockDim.x)
    atomicAdd(&h[levels[t]], 1);
  __syncthreads();
  if (threadIdx.x < NLVL) atomicAdd(&meta[threadIdx.x], h[threadIdx.x]);
}

__global__ void k_seg(int* meta) {
  if (threadIdx.x == 0 && blockIdx.x == 0) {
    int s = 0;
    for (int l = 0; l < NLVL; ++l) {
      int pc = (meta[l] + 255) & ~255;
      meta[8 + l] = s;
      meta[12 + l] = pc;
      s += pc;
    }
  }
}

__global__ void k_scatter(const int* __restrict__ levels, int n,
                          int* __restrict__ meta, int* __restrict__ idx) {
  __shared__ int h[NLVL], base[NLVL], cur[NLVL];
  int t = blockIdx.x * blockDim.x + threadIdx.x;
  if (threadIdx.x < NLVL) { h[threadIdx.x] = 0; cur[threadIdx.x] = 0; }
  __syncthreads();
  int lvl = 0;
  if (t < n) { lvl = levels[t]; atomicAdd(&h[lvl], 1); }
  __syncthreads();
  if (threadIdx.x < NLVL)
    base[threadIdx.x] = atomicAdd(&meta[4 + threadIdx.x], h[threadIdx.x]);
  __syncthreads();
  if (t < n) {
    int p = atomicAdd(&cur[lvl], 1);
    idx[meta[8 + lvl] + base[lvl] + p] = t;
  }
}

__global__ void k_cvt_x(const f32x4* __restrict__ x, u16x4* __restrict__ xb, int n4) {
  for (int t = blockIdx.x * blockDim.x + threadIdx.x; t < n4; t += gridDim.x * blockDim.x) {
    f32x4 v = x[t];
    u16x4 o;
    o[0] = f2bf(v[0]); o[1] = f2bf(v[1]); o[2] = f2bf(v[2]); o[3] = f2bf(v[3]);
    xb[t] = o;
  }
}

// transpose-convert W[lvl][k][n] (fp32) -> Wt[lvl][n][k] (bf16)
__global__ void k_twt(const float* __restrict__ W, unsigned short* __restrict__ Wt) {
  __shared__ float tile[32][33];
  int lvl = blockIdx.z;
  int k0 = blockIdx.x * 32, n0 = blockIdx.y * 32;
  int tx = threadIdx.x, ty = threadIdx.y;
  const float* Wp = W + (size_t)lvl * 1048576;
  unsigned short* Wtp = Wt + (size_t)lvl * 1048576;
#pragma unroll
  for (int i = 0; i < 4; ++i)
    tile[ty + i * 8][tx] = Wp[(size_t)(k0 + ty + i * 8) * 1024 + n0 + tx];
  __syncthreads();
#pragma unroll
  for (int i = 0; i < 4; ++i) {
    int nn = ty + i * 8;
    Wtp[(size_t)(n0 + nn) * 1024 + k0 + tx] = f2bf(tile[tx][nn]);
  }
}

// ---------------------------------------------------------------------------
// 256(m) x 256(n) grouped GEMM, BK=32, 16 waves (4m x 4n), per-wave 64x64,
// mfma 16x16x32 bf16, acc[4][4] f32x4 (88 VGPR at round-6 codegen; bound to
// <=128 so 4 waves/SIMD resident). 3-deep LDS pipeline, 96KB:
//   slot p in {0,1,2}: base p*32768; X [256r x 32k] at +0, W at +16384.
//   64B rows, chunk-XOR swizzle key (row&15)>>1 &3, applied on BOTH sides
//   (pre-swizzled global source chunk, linear gld_lds dest; same XOR on read).
// One phase per K-step (32 total): 8 ds_read_b128 + 2 gld_lds16 (stage tile
// t+2) | barrier | lgkmcnt(0) | 16 MFMA | counted vmcnt | barrier.
// Ledger (2 loads/wave/phase): prologue stages tiles 0,1 (4 loads), vmcnt(2).
// Phase t stages tile t+2 (loads #2t+5,2t+6); end-of-phase vmcnt(2) => done
// through #2t+4 = tile t+1's last load, exactly what phase t+1 reads.
// TAIL: staging stops after phase 29 (loads #63,64); phase 30 ends vmcnt(0)
// to drain them before phase 31 reads tile 31 (round-5 lesson: the counted
// window stops sliding when staging stops).
// Barriers are asm s_barrier with "memory" clobber (round-4 lesson).
// Rationale vs round 6 (475us/GEMM): staging-rate-bound at 10.9 B/cy/CU with
// 2 waves/SIMD; this doubles wave concurrency (4/SIMD) AND cuts staged bytes
// 3.17 -> 2.06 GB/GEMM (256^2 tile: 1MB staged per 134-MFLOP block).
// XCD-chunked grid (nb innermost): W window 4x512KB = 2MB L2-hot per XCD.
// ---------------------------------------------------------------------------
#define BARRM   asm volatile("s_barrier" ::: "memory")
#define WAIT_L  asm volatile("s_waitcnt lgkmcnt(0)" ::: "memory")
#define WAIT_V2 asm volatile("s_waitcnt vmcnt(2)" ::: "memory")
#define WAIT_V0 asm volatile("s_waitcnt vmcnt(0)" ::: "memory")
#define PRIO(x) __builtin_amdgcn_s_setprio(x)

#define RDW(p) { const char* p_ = lds + (p)*32768 + offW; \
  wf[0] = *(const bf16x8*)(p_);        wf[1] = *(const bf16x8*)(p_ + 1024);     \
  wf[2] = *(const bf16x8*)(p_ + 2048); wf[3] = *(const bf16x8*)(p_ + 3072); }
#define RDX(p) { const char* p_ = lds + (p)*32768 + offX;       \
  xf[0] = *(const bf16x8*)(p_);        xf[1] = *(const bf16x8*)(p_ + 1024);     \
  xf[2] = *(const bf16x8*)(p_ + 2048); xf[3] = *(const bf16x8*)(p_ + 3072); }
#define MMA4 { _Pragma("unroll") for (int nf_ = 0; nf_ < 4; ++nf_) { \
  _Pragma("unroll") for (int mf_ = 0; mf_ < 4; ++mf_) \
    acc[nf_][mf_] = __builtin_amdgcn_mfma_f32_16x16x32_bf16(wf[nf_], xf[mf_], acc[nf_][mf_], 0, 0, 0); } }
#define STG(p,t) { char* b_ = (char*)lds + (p)*32768 + (w << 10); \
  gld_lds16(xs0 + (t)*64, b_); \
  gld_lds16(ws0 + (t)*64, b_ + 16384); }

template <int PASS>
__global__ __launch_bounds__(1024, 4) void k_gemm(
    const unsigned short* __restrict__ Asrc,
    const unsigned short* __restrict__ Wt,
    const float* __restrict__ bias,
    const float* __restrict__ w3,
    const int* __restrict__ meta,
    const int* __restrict__ idx,
    unsigned short* __restrict__ hout,
    float* __restrict__ partial) {
  __shared__ __align__(16) char lds[98304];

  // XCD-chunked bijective swizzle over NSB*4 = 2064 blocks (2064 % 8 == 0).
  const int bid = blockIdx.x;
  const int swz = (bid & 7) * (NSB * NNB / 8) + (bid >> 3);
  const int nb = swz & 3;
  const int sb = swz >> 2;
  const int slotbase = sb * 256;
  if (slotbase >= meta[11] + meta[15]) return;
  int lvl;
  if      (slotbase < meta[9])  lvl = 0;
  else if (slotbase < meta[10]) lvl = 1;
  else if (slotbase < meta[11]) lvl = 2;
  else                          lvl = 3;

  const int tid = threadIdx.x;
  const int ln  = tid & 63;
  const int w   = tid >> 6;          // wave 0..15
  const int wm  = w & 3;             // m-quadrant (4 x 64 rows)
  const int wn  = w >> 2;            // n-quadrant (4 x 64 cols)
  const int l15 = ln & 15;

  // ---- staging lane constants: wave w stages X row & W row w*16+(ln>>2) ----
  const int srow = w * 16 + (ln >> 2);              // 0..255
  const int cch  = (ln & 3) ^ ((ln >> 3) & 3);      // pre-swizzled source chunk
  int ar0;
  if (PASS == 1) ar0 = idx[slotbase + srow];
  else           ar0 = slotbase + srow;
  const char* xs0 = (const char*)Asrc + (size_t)ar0 * 2048 + cch * 16;
  const char* ws0 = (const char*)Wt + ((size_t)lvl << 21)
                    + (size_t)(nb * 256 + srow) * 2048 + cch * 16;

  // ---- fragment read offsets (same XOR; +16 rows = +1024B) ----
  const int xorc = ((ln >> 4) ^ ((l15 >> 1) & 3)) * 16;
  const int offX = (wm * 64 + l15) * 64 + xorc;
  const int offW = 16384 + (wn * 64 + l15) * 64 + xorc;

  const f32x4 vzero = {0.f, 0.f, 0.f, 0.f};
  f32x4 acc[4][4];
#pragma unroll
  for (int a = 0; a < 4; ++a)
#pragma unroll
    for (int b = 0; b < 4; ++b) acc[a][b] = vzero;
  bf16x8 wf[4], xf[4];

  // ---- prologue: stage tiles 0 and 1 (2 loads each) ----
  STG(0, 0); STG(1, 1);
  WAIT_V2;                           // tile0's 2 loads landed
  BARRM;

  // ---- steady state: phases 0..29, staging t+2 ----
#pragma unroll
  for (int t = 0; t < 30; ++t) {
    const int p  = t % 3;
    const int ps = (t + 2) % 3;
    RDW(p); RDX(p);
    STG(ps, t + 2);
    BARRM; WAIT_L; PRIO(1); MMA4; PRIO(0); WAIT_V2; BARRM;
  }

  // ---- tail: phase 30 (drain) and 31 ----
  RDW(0); RDX(0);                    // tile 30, slot 30%3=0
  BARRM; WAIT_L; PRIO(1); MMA4; PRIO(0); WAIT_V0; BARRM;  // drain loads #63,64
  RDW(1); RDX(1);                    // tile 31, slot 1
  WAIT_L; PRIO(1); MMA4; PRIO(0);

  // ---- epilogue ----
  const float* bv = bias + lvl * 1024;
  const int n_lo = (ln >> 4) * 4;

  if (PASS == 1) {
#pragma unroll
    for (int nf = 0; nf < 4; ++nf) {
#pragma unroll
      for (int mf = 0; mf < 4; ++mf) {
        int slot = slotbase + wm * 64 + mf * 16 + l15;
        int col = nb * 256 + wn * 64 + nf * 16 + n_lo;
        f32x4 bb = *(const f32x4*)&bv[col];
        f32x4 v = acc[nf][mf];
        u16x4 o;
#pragma unroll
        for (int r = 0; r < 4; ++r) o[r] = f2bf(fmaxf(v[r] + bb[r], 0.f));
        *(u16x4*)&hout[(size_t)slot * 1024 + col] = o;
      }
    }
  } else {
    const float* w3v = w3 + lvl * 1024;
    float ps4[4] = {0.f, 0.f, 0.f, 0.f};
#pragma unroll
    for (int mf = 0; mf < 4; ++mf) {
#pragma unroll
      for (int nf = 0; nf < 4; ++nf) {
        int col = nb * 256 + wn * 64 + nf * 16 + n_lo;
        f32x4 bb = *(const f32x4*)&bv[col];
        f32x4 ww = *(const f32x4*)&w3v[col];
        f32x4 v = acc[nf][mf];
#pragma unroll
        for (int r = 0; r < 4; ++r) ps4[mf] += fmaxf(v[r] + bb[r], 0.f) * ww[r];
      }
    }
#pragma unroll
    for (int mf = 0; mf < 4; ++mf) {
      float p = ps4[mf];
      p += __shfl_xor(p, 16);
      p += __shfl_xor(p, 32);
      if (ln < 16) {
        int slot = slotbase + wm * 64 + mf * 16 + ln;
        partial[(size_t)slot * 16 + nb * 4 + wn] = p;
      }
    }
  }
}

__global__ void k_final(const int* __restrict__ meta, const int* __restrict__ idx,
                        const float* __restrict__ partial, const float* __restrict__ b3,
                        float* __restrict__ out) {
  int t = blockIdx.x * blockDim.x + threadIdx.x;
  int total = meta[11] + meta[15];
  if (t >= total) return;
  int lvl;
  if (t < meta[9]) lvl = 0;
  else if (t < meta[10]) lvl = 1;
  else if (t < meta[11]) lvl = 2;
  else lvl = 3;
  int local = t - meta[8 + lvl];
  if (local >= meta[lvl]) return;  // padding slot
  int row = idx[t];
  const float* pp = partial + (size_t)t * 16;
  float s = 0.f;
#pragma unroll
  for (int j = 0; j < 16; ++j) s += pp[j];
  out[row] = s + b3[lvl];
}

extern "C" void kernel_launch(void* const* d_in, const int* in_sizes, int n_in,
                              void* d_out, int out_size, void* d_ws, size_t ws_size,
                              hipStream_t stream) {
  const float* x      = (const float*)d_in[0];
  const int*   levels = (const int*)d_in[1];
  const float* W1     = (const float*)d_in[2];
  const float* b1     = (const float*)d_in[3];
  const float* W2     = (const float*)d_in[4];
  const float* b2     = (const float*)d_in[5];
  const float* W3     = (const float*)d_in[6];
  const float* b3     = (const float*)d_in[7];
  float* out = (float*)d_out;

  char* ws = (char*)d_ws;
  int* meta = (int*)ws;
  int* idx = (int*)(ws + OFF_IDX);
  float* partial = (float*)(ws + OFF_PART);
  unsigned short* Wt1 = (unsigned short*)(ws + OFF_WT1);
  unsigned short* Wt2 = (unsigned short*)(ws + OFF_WT2);
  unsigned short* xb  = (unsigned short*)(ws + OFF_XBF);
  unsigned short* h1  = (unsigned short*)(ws + OFF_H1);

  // zero meta + idx (padding slots -> row 0, safe finite data)
  hipMemsetAsync(d_ws, 0, OFF_IDX + (size_t)SLOT_CAP * 4, stream);
  k_hist<<<256, 256, 0, stream>>>(levels, NROWS, meta);
  k_seg<<<1, 64, 0, stream>>>(meta);
  k_scatter<<<512, 256, 0, stream>>>(levels, NROWS, meta, idx);
  k_cvt_x<<<2048, 256, 0, stream>>>((const f32x4*)x, (u16x4*)xb, NROWS * (KDIM / 4));
  k_twt<<<dim3(32, 32, 4), dim3(32, 8), 0, stream>>>(W1, Wt1);
  k_twt<<<dim3(32, 32, 4), dim3(32, 8), 0, stream>>>(W2, Wt2);

  k_gemm<1><<<NSB * NNB, 1024, 0, stream>>>(xb, Wt1, b1, nullptr, meta, idx, h1, nullptr);
  k_gemm<2><<<NSB * NNB, 1024, 0, stream>>>(h1, Wt2, b2, W3, meta, idx, nullptr, partial);

  k_final<<<516, 256, 0, stream>>>(meta, idx, partial, b3, out);
}

// Round 8
// 781.275 us; speedup vs baseline: 1.2269x; 1.0621x over previous
//
#include <hip/hip_runtime.h>

// ---------------- problem constants ----------------
#define NROWS   131072
#define KDIM    1024
#define NLVL    4
#define SLOT_CAP 132096            // 131072 + 4*256 padding
#define NSB     516                // SLOT_CAP / 256 slot-blocks
#define NNB     4                  // 1024 cols / 256

// ---------------- ws layout (bytes) ----------------
#define OFF_IDX  1024ull
#define OFF_PART (OFF_IDX + (size_t)SLOT_CAP * 4)
#define OFF_WT1  (OFF_PART + (size_t)SLOT_CAP * 64)
#define OFF_WT2  (OFF_WT1 + 8388608ull)
#define OFF_XBF  (OFF_WT2 + 8388608ull)
#define OFF_H1   (OFF_XBF + 268435456ull)

typedef __bf16 bf16x8 __attribute__((ext_vector_type(8)));
typedef float f32x4 __attribute__((ext_vector_type(4)));
typedef unsigned short u16x4 __attribute__((ext_vector_type(4)));

__device__ __forceinline__ unsigned short f2bf(float f) {
  unsigned int u = __float_as_uint(f);
  u += 0x7fffu + ((u >> 16) & 1u);       // RNE
  return (unsigned short)(u >> 16);
}

__device__ __forceinline__ void gld_lds16(const void* g, void* l) {
  __builtin_amdgcn_global_load_lds(
      (const __attribute__((address_space(1))) void*)g,
      (__attribute__((address_space(3))) void*)l, 16, 0, 0);
}

// meta layout (ints): [0..3]=counts [4..7]=cursors [8..11]=seg [12..15]=padded counts

__global__ void k_hist(const int* __restrict__ levels, int n, int* __restrict__ meta) {
  __shared__ int h[NLVL];
  if (threadIdx.x < NLVL) h[threadIdx.x] = 0;
  __syncthreads();
  for (int t = blockIdx.x * blockDim.x + threadIdx.x; t < n; t += gridDim.x * blockDim.x)
    atomicAdd(&h[levels[t]], 1);
  __syncthreads();
  if (threadIdx.x < NLVL) atomicAdd(&meta[threadIdx.x], h[threadIdx.x]);
}

__global__ void k_seg(int* meta) {
  if (threadIdx.x == 0 && blockIdx.x == 0) {
    int s = 0;
    for (int l = 0; l < NLVL; ++l) {
      int pc = (meta[l] + 255) & ~255;
      meta[8 + l] = s;
      meta[12 + l] = pc;
      s += pc;
    }
  }
}

__global__ void k_scatter(const int* __restrict__ levels, int n,
                          int* __restrict__ meta, int* __restrict__ idx) {
  __shared__ int h[NLVL], base[NLVL], cur[NLVL];
  int t = blockIdx.x * blockDim.x + threadIdx.x;
  if (threadIdx.x < NLVL) { h[threadIdx.x] = 0; cur[threadIdx.x] = 0; }
  __syncthreads();
  int lvl = 0;
  if (t < n) { lvl = levels[t]; atomicAdd(&h[lvl], 1); }
  __syncthreads();
  if (threadIdx.x < NLVL)
    base[threadIdx.x] = atomicAdd(&meta[4 + threadIdx.x], h[threadIdx.x]);
  __syncthreads();
  if (t < n) {
    int p = atomicAdd(&cur[lvl], 1);
    idx[meta[8 + lvl] + base[lvl] + p] = t;
  }
}

__global__ void k_cvt_x(const f32x4* __restrict__ x, u16x4* __restrict__ xb, int n4) {
  for (int t = blockIdx.x * blockDim.x + threadIdx.x; t < n4; t += gridDim.x * blockDim.x) {
    f32x4 v = x[t];
    u16x4 o;
    o[0] = f2bf(v[0]); o[1] = f2bf(v[1]); o[2] = f2bf(v[2]); o[3] = f2bf(v[3]);
    xb[t] = o;
  }
}

// transpose-convert W[lvl][k][n] (fp32) -> Wt[lvl][n][k] (bf16)
__global__ void k_twt(const float* __restrict__ W, unsigned short* __restrict__ Wt) {
  __shared__ float tile[32][33];
  int lvl = blockIdx.z;
  int k0 = blockIdx.x * 32, n0 = blockIdx.y * 32;
  int tx = threadIdx.x, ty = threadIdx.y;
  const float* Wp = W + (size_t)lvl * 1048576;
  unsigned short* Wtp = Wt + (size_t)lvl * 1048576;
#pragma unroll
  for (int i = 0; i < 4; ++i)
    tile[ty + i * 8][tx] = Wp[(size_t)(k0 + ty + i * 8) * 1024 + n0 + tx];
  __syncthreads();
#pragma unroll
  for (int i = 0; i < 4; ++i) {
    int nn = ty + i * 8;
    Wtp[(size_t)(n0 + nn) * 1024 + k0 + tx] = f2bf(tile[tx][nn]);
  }
}

// ---------------------------------------------------------------------------
// 256x256 grouped GEMM, BK=32, 16 waves (4m x 4n), per-wave 64x64,
// mfma 16x16x32 bf16, acc[4][4] f32x4 (AGPR). 3-deep LDS pipeline, 96KB.
// ROUND-8 CHANGE (m196 fine-interleave): single barrier per phase; phase =
//   STG(t+2) | ds_read g1(4) | ds_read g2(4) | lgkmcnt(4) | 4 MFMA (g1)
//   | lgkmcnt(0) | 12 MFMA | vmcnt(2) | barrier.
// g2's reads + both gld_lds16 drain UNDER the first MFMA cluster; MFMA and
// LDS no longer serialize. sched_barrier(0) after each counted wait pins the
// shape (rule #18: register-only MFMA can hoist past asm waitcnt).
// First barrier removed — WAR audit: slot (t+2)%3's old tile t-1 was read in
// phase t-1 and lgkm-drained before that phase's END barrier; stage writes
// are issued after it. RAW: each wave's end-of-phase vmcnt(2)+barrier still
// guarantees tile t+1 staged before phase t+1 reads it (ledger unchanged:
// 2 loads/wave/phase; prologue 4; tile j = loads #2j+1,2j+2; end of phase t
// vmcnt(2) => done through #2t+4 = tile t+1's last).
// TAIL (round-5 lesson): staging stops after phase 29; phase 30 ends
// vmcnt(0) to drain loads #63,64 before phase 31 reads tile 31.
// Barriers are asm s_barrier with "memory" clobber (round-4 lesson).
// Swizzle: 64B rows, chunk-XOR key on BOTH sides (pre-swizzled global
// source, linear gld_lds dest, same XOR on ds_read) -> conflict-free.
// XCD-chunked grid (nb innermost).
// ---------------------------------------------------------------------------
#define BARRM   asm volatile("s_barrier" ::: "memory")
#define WAIT_L4 asm volatile("s_waitcnt lgkmcnt(4)" ::: "memory")
#define WAIT_L0 asm volatile("s_waitcnt lgkmcnt(0)" ::: "memory")
#define WAIT_V2 asm volatile("s_waitcnt vmcnt(2)" ::: "memory")
#define WAIT_V0 asm volatile("s_waitcnt vmcnt(0)" ::: "memory")
#define SB0     __builtin_amdgcn_sched_barrier(0)
#define PRIO(x) __builtin_amdgcn_s_setprio(x)

#define RDG1(p) { const char* w_ = lds + (p)*32768 + offW; \
                  const char* x_ = lds + (p)*32768 + offX; \
  wf[0] = *(const bf16x8*)(w_);        wf[1] = *(const bf16x8*)(w_ + 1024);  \
  xf[0] = *(const bf16x8*)(x_);        xf[1] = *(const bf16x8*)(x_ + 1024); }
#define RDG2(p) { const char* w_ = lds + (p)*32768 + offW; \
                  const char* x_ = lds + (p)*32768 + offX; \
  wf[2] = *(const bf16x8*)(w_ + 2048); wf[3] = *(const bf16x8*)(w_ + 3072); \
  xf[2] = *(const bf16x8*)(x_ + 2048); xf[3] = *(const bf16x8*)(x_ + 3072); }
#define MMA(nf_,mf_) acc[nf_][mf_] = __builtin_amdgcn_mfma_f32_16x16x32_bf16(wf[nf_], xf[mf_], acc[nf_][mf_], 0, 0, 0)
#define MMA_G1 { MMA(0,0); MMA(0,1); MMA(1,0); MMA(1,1); }
#define MMA_G2 { MMA(0,2); MMA(0,3); MMA(1,2); MMA(1,3); \
                 MMA(2,0); MMA(2,1); MMA(2,2); MMA(2,3); \
                 MMA(3,0); MMA(3,1); MMA(3,2); MMA(3,3); }
#define STG(p,t) { char* b_ = (char*)lds + (p)*32768 + (w << 10); \
  gld_lds16(xs0 + (t)*64, b_); \
  gld_lds16(ws0 + (t)*64, b_ + 16384); }

#define PHASE_CORE(p) \
  RDG1(p); RDG2(p); \
  WAIT_L4; SB0; \
  PRIO(1); MMA_G1; \
  WAIT_L0; SB0; \
  MMA_G2; PRIO(0);

template <int PASS>
__global__ __launch_bounds__(1024, 4) void k_gemm(
    const unsigned short* __restrict__ Asrc,
    const unsigned short* __restrict__ Wt,
    const float* __restrict__ bias,
    const float* __restrict__ w3,
    const int* __restrict__ meta,
    const int* __restrict__ idx,
    unsigned short* __restrict__ hout,
    float* __restrict__ partial) {
  __shared__ __align__(16) char lds[98304];

  // XCD-chunked bijective swizzle over NSB*4 = 2064 blocks (2064 % 8 == 0).
  const int bid = blockIdx.x;
  const int swz = (bid & 7) * (NSB * NNB / 8) + (bid >> 3);
  const int nb = swz & 3;
  const int sb = swz >> 2;
  const int slotbase = sb * 256;
  if (slotbase >= meta[11] + meta[15]) return;
  int lvl;
  if      (slotbase < meta[9])  lvl = 0;
  else if (slotbase < meta[10]) lvl = 1;
  else if (slotbase < meta[11]) lvl = 2;
  else                          lvl = 3;

  const int tid = threadIdx.x;
  const int ln  = tid & 63;
  const int w   = tid >> 6;          // wave 0..15
  const int wm  = w & 3;             // m-quadrant (4 x 64 rows)
  const int wn  = w >> 2;            // n-quadrant (4 x 64 cols)
  const int l15 = ln & 15;

  // ---- staging lane constants: wave w stages X row & W row w*16+(ln>>2) ----
  const int srow = w * 16 + (ln >> 2);              // 0..255
  const int cch  = (ln & 3) ^ ((ln >> 3) & 3);      // pre-swizzled source chunk
  int ar0;
  if (PASS == 1) ar0 = idx[slotbase + srow];
  else           ar0 = slotbase + srow;
  const char* xs0 = (const char*)Asrc + (size_t)ar0 * 2048 + cch * 16;
  const char* ws0 = (const char*)Wt + ((size_t)lvl << 21)
                    + (size_t)(nb * 256 + srow) * 2048 + cch * 16;

  // ---- fragment read offsets (same XOR; +16 rows = +1024B) ----
  const int xorc = ((ln >> 4) ^ ((l15 >> 1) & 3)) * 16;
  const int offX = (wm * 64 + l15) * 64 + xorc;
  const int offW = 16384 + (wn * 64 + l15) * 64 + xorc;

  const f32x4 vzero = {0.f, 0.f, 0.f, 0.f};
  f32x4 acc[4][4];
#pragma unroll
  for (int a = 0; a < 4; ++a)
#pragma unroll
    for (int b = 0; b < 4; ++b) acc[a][b] = vzero;
  bf16x8 wf[4], xf[4];

  // ---- prologue: stage tiles 0 and 1 (2 loads each) ----
  STG(0, 0); STG(1, 1);
  WAIT_V2;                           // tile0's 2 loads landed
  BARRM;

  // ---- steady state: phases 0..29, staging t+2 ----
#pragma unroll
  for (int t = 0; t < 30; ++t) {
    const int p  = t % 3;
    const int ps = (t + 2) % 3;
    STG(ps, t + 2);
    PHASE_CORE(p);
    WAIT_V2; BARRM;
  }

  // ---- tail: phase 30 (drain) and 31 ----
  PHASE_CORE(0);                     // tile 30, slot 0
  WAIT_V0; BARRM;                    // drain loads #63,64
  PHASE_CORE(1);                     // tile 31, slot 1

  // ---- epilogue ----
  const float* bv = bias + lvl * 1024;
  const int n_lo = (ln >> 4) * 4;

  if (PASS == 1) {
#pragma unroll
    for (int nf = 0; nf < 4; ++nf) {
#pragma unroll
      for (int mf = 0; mf < 4; ++mf) {
        int slot = slotbase + wm * 64 + mf * 16 + l15;
        int col = nb * 256 + wn * 64 + nf * 16 + n_lo;
        f32x4 bb = *(const f32x4*)&bv[col];
        f32x4 v = acc[nf][mf];
        u16x4 o;
#pragma unroll
        for (int r = 0; r < 4; ++r) o[r] = f2bf(fmaxf(v[r] + bb[r], 0.f));
        *(u16x4*)&hout[(size_t)slot * 1024 + col] = o;
      }
    }
  } else {
    const float* w3v = w3 + lvl * 1024;
    float ps4[4] = {0.f, 0.f, 0.f, 0.f};
#pragma unroll
    for (int mf = 0; mf < 4; ++mf) {
#pragma unroll
      for (int nf = 0; nf < 4; ++nf) {
        int col = nb * 256 + wn * 64 + nf * 16 + n_lo;
        f32x4 bb = *(const f32x4*)&bv[col];
        f32x4 ww = *(const f32x4*)&w3v[col];
        f32x4 v = acc[nf][mf];
#pragma unroll
        for (int r = 0; r < 4; ++r) ps4[mf] += fmaxf(v[r] + bb[r], 0.f) * ww[r];
      }
    }
#pragma unroll
    for (int mf = 0; mf < 4; ++mf) {
      float p = ps4[mf];
      p += __shfl_xor(p, 16);
      p += __shfl_xor(p, 32);
      if (ln < 16) {
        int slot = slotbase + wm * 64 + mf * 16 + ln;
        partial[(size_t)slot * 16 + nb * 4 + wn] = p;
      }
    }
  }
}

__global__ void k_final(const int* __restrict__ meta, const int* __restrict__ idx,
                        const float* __restrict__ partial, const float* __restrict__ b3,
                        float* __restrict__ out) {
  int t = blockIdx.x * blockDim.x + threadIdx.x;
  int total = meta[11] + meta[15];
  if (t >= total) return;
  int lvl;
  if (t < meta[9]) lvl = 0;
  else if (t < meta[10]) lvl = 1;
  else if (t < meta[11]) lvl = 2;
  else lvl = 3;
  int local = t - meta[8 + lvl];
  if (local >= meta[lvl]) return;  // padding slot
  int row = idx[t];
  const float* pp = partial + (size_t)t * 16;
  float s = 0.f;
#pragma unroll
  for (int j = 0; j < 16; ++j) s += pp[j];
  out[row] = s + b3[lvl];
}

extern "C" void kernel_launch(void* const* d_in, const int* in_sizes, int n_in,
                              void* d_out, int out_size, void* d_ws, size_t ws_size,
                              hipStream_t stream) {
  const float* x      = (const float*)d_in[0];
  const int*   levels = (const int*)d_in[1];
  const float* W1     = (const float*)d_in[2];
  const float* b1     = (const float*)d_in[3];
  const float* W2     = (const float*)d_in[4];
  const float* b2     = (const float*)d_in[5];
  const float* W3     = (const float*)d_in[6];
  const float* b3     = (const float*)d_in[7];
  float* out = (float*)d_out;

  char* ws = (char*)d_ws;
  int* meta = (int*)ws;
  int* idx = (int*)(ws + OFF_IDX);
  float* partial = (float*)(ws + OFF_PART);
  unsigned short* Wt1 = (unsigned short*)(ws + OFF_WT1);
  unsigned short* Wt2 = (unsigned short*)(ws + OFF_WT2);
  unsigned short* xb  = (unsigned short*)(ws + OFF_XBF);
  unsigned short* h1  = (unsigned short*)(ws + OFF_H1);

  // zero meta + idx (padding slots -> row 0, safe finite data)
  hipMemsetAsync(d_ws, 0, OFF_IDX + (size_t)SLOT_CAP * 4, stream);
  k_hist<<<256, 256, 0, stream>>>(levels, NROWS, meta);
  k_seg<<<1, 64, 0, stream>>>(meta);
  k_scatter<<<512, 256, 0, stream>>>(levels, NROWS, meta, idx);
  k_cvt_x<<<2048, 256, 0, stream>>>((const f32x4*)x, (u16x4*)xb, NROWS * (KDIM / 4));
  k_twt<<<dim3(32, 32, 4), dim3(32, 8), 0, stream>>>(W1, Wt1);
  k_twt<<<dim3(32, 32, 4), dim3(32, 8), 0, stream>>>(W2, Wt2);

  k_gemm<1><<<NSB * NNB, 1024, 0, stream>>>(xb, Wt1, b1, nullptr, meta, idx, h1, nullptr);
  k_gemm<2><<<NSB * NNB, 1024, 0, stream>>>(h1, Wt2, b2, W3, meta, idx, nullptr, partial);

  k_final<<<516, 256, 0, stream>>>(meta, idx, partial, b3, out);
}